// Round 1
// baseline (103.961 us; speedup 1.0000x reference)
//
#include <hip/hip_runtime.h>

#define T_LEN     2000000
#define NT        5
#define START_TAG 3
#define STOP_TAG  4
#define CHUNK     16
#define NBLK      512
#define BTHR      256
#define WS_G_OFF  (NBLK * 26)   // float offset of gold partials in ws

// Compose two scaled transfer matrices: C = L @ R (L is the LATER chunk),
// entries are probabilities (max-normalized), slot 25 is the log-offset.
__device__ __forceinline__ void compose26(const float* Lm, const float* Rm, float* C) {
#pragma unroll
    for (int j = 0; j < NT; ++j) {
#pragma unroll
        for (int s = 0; s < NT; ++s) {
            float acc = Lm[j * NT + 0] * Rm[0 * NT + s];
#pragma unroll
            for (int i = 1; i < NT; ++i)
                acc = fmaf(Lm[j * NT + i], Rm[i * NT + s], acc);
            C[j * NT + s] = acc;
        }
    }
    float m = C[0];
#pragma unroll
    for (int k = 1; k < 25; ++k) m = fmaxf(m, C[k]);
    float r = 1.0f / m;
#pragma unroll
    for (int k = 0; k < 25; ++k) C[k] *= r;
    C[25] = Lm[25] + Rm[25] + __logf(m);
}

__global__ __launch_bounds__(BTHR) void crf_phase1(
    const float* __restrict__ feats, const int* __restrict__ tags,
    const float* __restrict__ trans, float* __restrict__ ws)
{
    __shared__ float sTr[NT * NT];
    __shared__ float sM[BTHR][26];
    __shared__ float sG[BTHR];

    const int tid = threadIdx.x;
    if (tid < NT * NT) sTr[tid] = trans[tid];
    __syncthreads();

    const int  gtid  = blockIdx.x * BTHR + tid;
    const long start = (long)gtid * CHUNK;

    // A = identity (log-semiring identity in prob domain), offset 0
    float A[NT * NT];
#pragma unroll
    for (int k = 0; k < NT * NT; ++k) A[k] = 0.0f;
#pragma unroll
    for (int k = 0; k < NT; ++k) A[k * NT + k] = 1.0f;
    float off  = 0.0f;
    float gold = 0.0f;

    if (start < T_LEN) {
        float E[NT * NT];
#pragma unroll
        for (int k = 0; k < NT * NT; ++k) E[k] = __expf(sTr[k]);  // exp(-10000)=0 handles semiring zero

        int prev = (start == 0) ? START_TAG : tags[start - 1];
        const float* fp = feats + (size_t)start * NT;

#pragma unroll
        for (int h = 0; h < CHUNK / 8; ++h) {
#pragma unroll
            for (int st = 0; st < 8; ++st) {
                const int t = h * 8 + st;
                float f[NT], e[NT];
#pragma unroll
                for (int j = 0; j < NT; ++j) f[j] = fp[t * NT + j];
#pragma unroll
                for (int j = 0; j < NT; ++j) e[j] = __expf(f[j]);

                float N[NT * NT];
#pragma unroll
                for (int j = 0; j < NT; ++j) {
#pragma unroll
                    for (int s = 0; s < NT; ++s) {
                        float acc = E[j * NT + 0] * A[0 * NT + s];
#pragma unroll
                        for (int i = 1; i < NT; ++i)
                            acc = fmaf(E[j * NT + i], A[i * NT + s], acc);
                        N[j * NT + s] = e[j] * acc;
                    }
                }
#pragma unroll
                for (int k = 0; k < NT * NT; ++k) A[k] = N[k];

                // gold score slice (tags are in {0,1,2})
                const int tg  = tags[start + t];
                const float ftg = (tg == 0) ? f[0] : ((tg == 1) ? f[1] : f[2]);
                gold += sTr[tg * NT + prev] + ftg;
                prev = tg;
            }
            // rescale every 8 steps (worst-case growth e^9.2/step -> safe)
            float m = A[0];
#pragma unroll
            for (int k = 1; k < 25; ++k) m = fmaxf(m, A[k]);
            const float r = 1.0f / m;
#pragma unroll
            for (int k = 0; k < 25; ++k) A[k] *= r;
            off += __logf(m);
        }
        if (start + CHUNK == T_LEN) gold += sTr[STOP_TAG * NT + prev];  // final STOP transition
    }

    // ---- block-level in-order tree reduce ----
#pragma unroll
    for (int k = 0; k < 25; ++k) sM[tid][k] = A[k];
    sM[tid][25] = off;
    sG[tid]     = gold;
    __syncthreads();

    for (int h = BTHR / 2; h >= 1; h >>= 1) {
        float C[26];
        float gg = 0.0f;
        const bool act = (tid < h);
        if (act) {
            float Lm[26], Rm[26];
#pragma unroll
            for (int k = 0; k < 26; ++k) { Lm[k] = sM[2 * tid + 1][k]; Rm[k] = sM[2 * tid][k]; }
            compose26(Lm, Rm, C);
            gg = sG[2 * tid] + sG[2 * tid + 1];
        }
        __syncthreads();
        if (act) {
#pragma unroll
            for (int k = 0; k < 26; ++k) sM[tid][k] = C[k];
            sG[tid] = gg;
        }
        __syncthreads();
    }

    if (tid < 26) ws[blockIdx.x * 26 + tid] = sM[0][tid];
    if (tid == 0) ws[WS_G_OFF + blockIdx.x] = sG[0];
}

__global__ __launch_bounds__(256) void crf_phase2(
    const float* __restrict__ trans, const float* __restrict__ ws,
    float* __restrict__ out)
{
    __shared__ float sM[256][26];
    __shared__ float sG[256];

    const int tid = threadIdx.x;

    // each thread composes block-matrix pair (2*tid, 2*tid+1), later on the left
    {
        float Lm[26], Rm[26], C[26];
#pragma unroll
        for (int k = 0; k < 26; ++k) {
            Lm[k] = ws[(2 * tid + 1) * 26 + k];
            Rm[k] = ws[(2 * tid) * 26 + k];
        }
        compose26(Lm, Rm, C);
#pragma unroll
        for (int k = 0; k < 26; ++k) sM[tid][k] = C[k];
        sG[tid] = ws[WS_G_OFF + 2 * tid] + ws[WS_G_OFF + 2 * tid + 1];
    }
    __syncthreads();

    for (int h = 128; h >= 1; h >>= 1) {
        float C[26];
        float gg = 0.0f;
        const bool act = (tid < h);
        if (act) {
            float Lm[26], Rm[26];
#pragma unroll
            for (int k = 0; k < 26; ++k) { Lm[k] = sM[2 * tid + 1][k]; Rm[k] = sM[2 * tid][k]; }
            compose26(Lm, Rm, C);
            gg = sG[2 * tid] + sG[2 * tid + 1];
        }
        __syncthreads();
        if (act) {
#pragma unroll
            for (int k = 0; k < 26; ++k) sM[tid][k] = C[k];
            sG[tid] = gg;
        }
        __syncthreads();
    }

    if (tid == 0) {
        // alpha = off + log( sum_j P[j][START] * exp(trans[STOP][j]) )
        float s = 0.0f;
#pragma unroll
        for (int j = 0; j < NT; ++j)
            s += sM[0][j * NT + START_TAG] * __expf(trans[STOP_TAG * NT + j]);
        const float alpha = sM[0][25] + __logf(s);
        out[0] = alpha - sG[0];
    }
}

extern "C" void kernel_launch(void* const* d_in, const int* in_sizes, int n_in,
                              void* d_out, int out_size, void* d_ws, size_t ws_size,
                              hipStream_t stream) {
    const float* feats = (const float*)d_in[0];
    const int*   tags  = (const int*)d_in[1];
    const float* trans = (const float*)d_in[2];
    float*       out   = (float*)d_out;
    float*       ws    = (float*)d_ws;

    crf_phase1<<<NBLK, BTHR, 0, stream>>>(feats, tags, trans, ws);
    crf_phase2<<<1, 256, 0, stream>>>(trans, ws, out);
}

// Round 2
// 100.206 us; speedup vs baseline: 1.0375x; 1.0375x over previous
//
#include <hip/hip_runtime.h>

#define T_LEN     2000000
#define NT        5
#define START_TAG 3
#define STOP_TAG  4
#define CH        8              // time steps per thread
#define BTHR      256
#define NBLK      1024           // 1024*256*8 >= 2e6
#define SPB       (BTHR * CH)    // 2048 steps per block
#define GOFF      (NBLK * 13)    // float offset of gold partials in ws
#define ID_OFF    (-1.0e30f)     // sentinel: identity element

// Reduced scaled transfer matrix: rows {0,1,2} x cols {0,1,2,START}, slot 12 =
// log offset. Rows START/STOP and col STOP are identically zero (exp(NEG)=0)
// and never contribute to alpha, so they are dropped. off < -1e29 = identity.
__device__ __forceinline__ void compose13(const float* L, const float* R, float* C) {
    float t[12];
#pragma unroll
    for (int j = 0; j < 3; ++j)
#pragma unroll
        for (int s = 0; s < 4; ++s)
            t[j * 4 + s] = fmaf(L[j * 4 + 0], R[0 * 4 + s],
                           fmaf(L[j * 4 + 1], R[1 * 4 + s],
                                L[j * 4 + 2] * R[2 * 4 + s]));
    float m = t[0];
#pragma unroll
    for (int k = 1; k < 12; ++k) m = fmaxf(m, t[k]);
    const float r    = 1.0f / m;
    const float toff = L[12] + R[12] + __logf(m);
    const bool  Lid  = L[12] < -1e29f;
    const bool  Rid  = R[12] < -1e29f;
#pragma unroll
    for (int k = 0; k < 12; ++k)
        C[k] = Rid ? L[k] : (Lid ? R[k] : t[k] * r);
    C[12] = Rid ? L[12] : (Lid ? R[12] : toff);
}

__global__ __launch_bounds__(BTHR) void crf_phase1(
    const float* __restrict__ feats, const int* __restrict__ tags,
    const float* __restrict__ trans, float* __restrict__ ws)
{
    // stage buffers (51200 B) aliased with reduce buffers (14336 B)
    __shared__ __align__(16) char smem[BTHR * 41 * 4 + BTHR * 9 * 4];
    __shared__ float sTr[NT * NT];

    float* sF  = (float*)smem;                  // [256][41] padded feats (40 dwords/thread)
    int*   sTg = (int*)(smem + BTHR * 41 * 4);  // [256][9]  padded tags  (8/thread)

    const int tid = threadIdx.x;
    if (tid < NT * NT) sTr[tid] = trans[tid];

    const long blockBase = (long)blockIdx.x * SPB;       // first time step of block
    // ---- coalesced staging: feats (40 KB) ----
    {
        const float* gF   = feats + blockBase * NT;
        const long   remL = (long)T_LEN * NT - blockBase * NT;
        const int    remF = (int)(remL < 0 ? 0 : (remL > SPB * NT ? SPB * NT : remL));
#pragma unroll
        for (int k = 0; k < 10; ++k) {
            const int dw = (tid + k * BTHR) * 4;         // dword index, %4==0; remF%4==0
            if (dw < remF) {
                const float4 v = *(const float4*)(gF + dw);
                const int row = dw / 40;
                const int col = dw - row * 40;
                float* d = sF + row * 41 + col;
                d[0] = v.x; d[1] = v.y; d[2] = v.z; d[3] = v.w;
            }
        }
    }
    // ---- coalesced staging: tags (8 KB) ----
    {
        const int* gT   = tags + blockBase;
        const long remL = (long)T_LEN - blockBase;
        const int  remT = (int)(remL < 0 ? 0 : (remL > SPB ? SPB : remL));
#pragma unroll
        for (int k = 0; k < 2; ++k) {
            const int idx = (tid + k * BTHR) * 4;        // %4==0; remT%4==0
            if (idx < remT) {
                const int4 v = *(const int4*)(gT + idx);
                int* d = sTg + (idx >> 3) * 9 + (idx & 7);
                d[0] = v.x; d[1] = v.y; d[2] = v.z; d[3] = v.w;
            }
        }
    }
    __syncthreads();

    const long start  = blockBase + (long)tid * CH;
    const bool active = (start < T_LEN);                 // active chunks are always full (2e6 % 8 == 0)

    float A[12];
    float off  = ID_OFF;
    float gold = 0.0f;

    if (active) {
        // E[j][s] = exp(trans[j][s]), j in {0,1,2}, s in {0,1,2,START}
        float E[12];
#pragma unroll
        for (int j = 0; j < 3; ++j)
#pragma unroll
            for (int s = 0; s < 4; ++s)
                E[j * 4 + s] = __expf(sTr[j * NT + s]);

        const float* myF = sF + tid * 41;
        const int*   myT = sTg + tid * 9;

        int prev;
        if (tid > 0)            prev = sTg[(tid - 1) * 9 + (CH - 1)];
        else if (blockIdx.x)    prev = tags[start - 1];
        else                    prev = START_TAG;

        // step 0: A = diag(e) * E   (A_prev = I, only rows {0,1,2}, cols {0..3} live)
        {
            const float f0 = myF[0], f1 = myF[1], f2 = myF[2];
            const float e0 = __expf(f0), e1 = __expf(f1), e2 = __expf(f2);
#pragma unroll
            for (int s = 0; s < 4; ++s) {
                A[0 * 4 + s] = e0 * E[0 * 4 + s];
                A[1 * 4 + s] = e1 * E[1 * 4 + s];
                A[2 * 4 + s] = e2 * E[2 * 4 + s];
            }
            const int tg = myT[0];
            gold = sTr[tg * NT + prev] + (tg == 0 ? f0 : (tg == 1 ? f1 : f2));
            prev = tg;
        }
        // steps 1..7
#pragma unroll
        for (int t = 1; t < CH; ++t) {
            const float f0 = myF[t * 5 + 0], f1 = myF[t * 5 + 1], f2 = myF[t * 5 + 2];
            const float e0 = __expf(f0), e1 = __expf(f1), e2 = __expf(f2);
            float N[12];
#pragma unroll
            for (int s = 0; s < 4; ++s) {
                const float a0 = A[0 * 4 + s], a1 = A[1 * 4 + s], a2 = A[2 * 4 + s];
                N[0 * 4 + s] = e0 * fmaf(E[0], a0, fmaf(E[1], a1, E[2] * a2));
                N[1 * 4 + s] = e1 * fmaf(E[4], a0, fmaf(E[5], a1, E[6] * a2));
                N[2 * 4 + s] = e2 * fmaf(E[8], a0, fmaf(E[9], a1, E[10] * a2));
            }
#pragma unroll
            for (int k = 0; k < 12; ++k) A[k] = N[k];

            const int tg = myT[t];
            gold += sTr[tg * NT + prev] + (tg == 0 ? f0 : (tg == 1 ? f1 : f2));
            prev = tg;
        }
        // normalize once per chunk (max growth ~e^75 from 1.0 — safe in fp32)
        float m = A[0];
#pragma unroll
        for (int k = 1; k < 12; ++k) m = fmaxf(m, A[k]);
        const float r = 1.0f / m;
#pragma unroll
        for (int k = 0; k < 12; ++k) A[k] *= r;
        off = __logf(m);

        if (start + CH == T_LEN) gold += sTr[STOP_TAG * NT + prev];
    } else {
#pragma unroll
        for (int k = 0; k < 12; ++k) A[k] = 0.0f;
    }

    // ---- block tree reduce (in time order), aliasing the stage buffers ----
    __syncthreads();                                     // done with sF/sTg
    float* sM = (float*)smem;                            // [256][13]
    float* sG = (float*)(smem + BTHR * 13 * 4);          // [256]

#pragma unroll
    for (int k = 0; k < 12; ++k) sM[tid * 13 + k] = A[k];
    sM[tid * 13 + 12] = off;
    sG[tid]           = gold;
    __syncthreads();

    for (int h = BTHR / 2; h >= 1; h >>= 1) {
        float C[13];
        float gg = 0.0f;
        const bool act = (tid < h);
        if (act) {
            float L[13], R[13];
#pragma unroll
            for (int k = 0; k < 13; ++k) {
                L[k] = sM[(2 * tid + 1) * 13 + k];
                R[k] = sM[(2 * tid) * 13 + k];
            }
            compose13(L, R, C);
            gg = sG[2 * tid] + sG[2 * tid + 1];
        }
        __syncthreads();
        if (act) {
#pragma unroll
            for (int k = 0; k < 13; ++k) sM[tid * 13 + k] = C[k];
            sG[tid] = gg;
        }
        __syncthreads();
    }

    if (tid < 13) ws[blockIdx.x * 13 + tid] = sM[tid];
    if (tid == 0) ws[GOFF + blockIdx.x] = sG[0];
}

__global__ __launch_bounds__(256) void crf_phase2(
    const float* __restrict__ trans, const float* __restrict__ ws,
    float* __restrict__ out)
{
    __shared__ float sM[256 * 13];
    __shared__ float sG[256];

    const int tid = threadIdx.x;

    // each thread composes 4 consecutive block matrices in time order
    {
        float acc[13], nxt[13], C[13];
#pragma unroll
        for (int k = 0; k < 13; ++k) acc[k] = ws[(4 * tid) * 13 + k];
        float gg = ws[GOFF + 4 * tid];
#pragma unroll
        for (int g = 1; g < 4; ++g) {
#pragma unroll
            for (int k = 0; k < 13; ++k) nxt[k] = ws[(4 * tid + g) * 13 + k];
            compose13(nxt, acc, C);
#pragma unroll
            for (int k = 0; k < 13; ++k) acc[k] = C[k];
            gg += ws[GOFF + 4 * tid + g];
        }
#pragma unroll
        for (int k = 0; k < 13; ++k) sM[tid * 13 + k] = acc[k];
        sG[tid] = gg;
    }
    __syncthreads();

    for (int h = 128; h >= 1; h >>= 1) {
        float C[13];
        float gg = 0.0f;
        const bool act = (tid < h);
        if (act) {
            float L[13], R[13];
#pragma unroll
            for (int k = 0; k < 13; ++k) {
                L[k] = sM[(2 * tid + 1) * 13 + k];
                R[k] = sM[(2 * tid) * 13 + k];
            }
            compose13(L, R, C);
            gg = sG[2 * tid] + sG[2 * tid + 1];
        }
        __syncthreads();
        if (act) {
#pragma unroll
            for (int k = 0; k < 13; ++k) sM[tid * 13 + k] = C[k];
            sG[tid] = gg;
        }
        __syncthreads();
    }

    if (tid == 0) {
        // alpha = off + log( sum_{j<3} M[j][START] * exp(trans[STOP][j]) )
        float s = 0.0f;
#pragma unroll
        for (int j = 0; j < 3; ++j)
            s += sM[j * 4 + 3] * __expf(trans[STOP_TAG * NT + j]);
        const float alpha = sM[12] + __logf(s);
        out[0] = alpha - sG[0];
    }
}

extern "C" void kernel_launch(void* const* d_in, const int* in_sizes, int n_in,
                              void* d_out, int out_size, void* d_ws, size_t ws_size,
                              hipStream_t stream) {
    const float* feats = (const float*)d_in[0];
    const int*   tags  = (const int*)d_in[1];
    const float* trans = (const float*)d_in[2];
    float*       out   = (float*)d_out;
    float*       ws    = (float*)d_ws;

    crf_phase1<<<NBLK, BTHR, 0, stream>>>(feats, tags, trans, ws);
    crf_phase2<<<1, 256, 0, stream>>>(trans, ws, out);
}

// Round 3
// 98.814 us; speedup vs baseline: 1.0521x; 1.0141x over previous
//
#include <hip/hip_runtime.h>

#define T_LEN     2000000
#define NT        5
#define START_TAG 3
#define STOP_TAG  4
#define CH        8              // time steps per thread
#define BTHR      256
#define NBLK      1024           // 1024*256*8 = 2,097,152 >= 2e6; 4 blocks/CU, all resident
#define SPB       (BTHR * CH)    // 2048 steps per block
#define GOFF      (NBLK * 13)    // float offset of gold partials in ws
#define ID_OFF    (-1.0e30f)     // sentinel: identity element
#define FSTR      25             // LDS floats per thread-chunk: 8 steps * 3 cols + 1 pad (odd -> conflict-free)

// Reduced scaled transfer matrix: rows {0,1,2} x cols {0,1,2,START}, slot 12 =
// log offset. Rows START/STOP and col STOP are semiring-zero (exp(NEG)=0) and
// contribute nothing to alpha, so they are dropped. off < -1e29 = identity.
__device__ __forceinline__ void compose13(const float* L, const float* R, float* C) {
    float t[12];
#pragma unroll
    for (int j = 0; j < 3; ++j)
#pragma unroll
        for (int s = 0; s < 4; ++s)
            t[j * 4 + s] = fmaf(L[j * 4 + 0], R[0 * 4 + s],
                           fmaf(L[j * 4 + 1], R[1 * 4 + s],
                                L[j * 4 + 2] * R[2 * 4 + s]));
    float m = t[0];
#pragma unroll
    for (int k = 1; k < 12; ++k) m = fmaxf(m, t[k]);
    const float r    = 1.0f / m;
    const float toff = L[12] + R[12] + __logf(m);
    const bool  Lid  = L[12] < -1e29f;
    const bool  Rid  = R[12] < -1e29f;
#pragma unroll
    for (int k = 0; k < 12; ++k)
        C[k] = Rid ? L[k] : (Lid ? R[k] : t[k] * r);
    C[12] = Rid ? L[12] : (Lid ? R[12] : toff);
}

__global__ __launch_bounds__(BTHR) void crf_phase1(
    const float* __restrict__ feats, const int* __restrict__ tags,
    const float* __restrict__ trans, float* __restrict__ ws)
{
    // stage buffers (34816 B) aliased with reduce buffers (14336 B); 4 blocks/CU
    __shared__ __align__(16) char smem[BTHR * FSTR * 4 + BTHR * 9 * 4];
    __shared__ float sTr[NT * NT];

    float* sF  = (float*)smem;                       // [256][25]: cols {0,1,2} of 8 steps, +1 pad
    int*   sTg = (int*)(smem + BTHR * FSTR * 4);     // [256][9]:  8 tags + 1 pad

    const int tid = threadIdx.x;
    if (tid < NT * NT) sTr[tid] = trans[tid];

    const long blockBase = (long)blockIdx.x * SPB;

    // ---- coalesced staging: feats (40 KB global -> 24 KB LDS, cols 0..2 only) ----
    {
        const float* gF   = feats + blockBase * NT;
        const long   remL = (long)T_LEN * NT - blockBase * NT;
        const int    remF = (int)(remL < 0 ? 0 : (remL > SPB * NT ? SPB * NT : remL));
#pragma unroll
        for (int k = 0; k < 10; ++k) {
            const int dw = (tid + k * BTHR) * 4;     // remF % 4 == 0 always
            if (dw < remF) {
                const float4 v = *(const float4*)(gF + dw);
                const float vv[4] = {v.x, v.y, v.z, v.w};
#pragma unroll
                for (int e = 0; e < 4; ++e) {
                    const int x    = dw + e;
                    const int step = x / 5;          // constant div -> magic mul
                    const int c    = x - step * 5;
                    if (c < 3)
                        sF[(step >> 3) * FSTR + (step & 7) * 3 + c] = vv[e];
                }
            }
        }
    }
    // ---- coalesced staging: tags (8 KB) ----
    {
        const int* gT   = tags + blockBase;
        const long remL = (long)T_LEN - blockBase;
        const int  remT = (int)(remL < 0 ? 0 : (remL > SPB ? SPB : remL));
#pragma unroll
        for (int k = 0; k < 2; ++k) {
            const int idx = (tid + k * BTHR) * 4;    // remT % 4 == 0 always
            if (idx < remT) {
                const int4 v = *(const int4*)(gT + idx);
                int* d = sTg + (idx >> 3) * 9 + (idx & 7);
                d[0] = v.x; d[1] = v.y; d[2] = v.z; d[3] = v.w;
            }
        }
    }
    __syncthreads();

    const long start  = blockBase + (long)tid * CH;
    const bool active = (start < T_LEN);             // active chunks always full (2e6 % 8 == 0)

    float A[12];
    float off  = ID_OFF;
    float gold = 0.0f;

    if (active) {
        // E[j][s] = exp(trans[j][s]), j in {0,1,2}, s in {0,1,2,START}
        float E[12];
#pragma unroll
        for (int j = 0; j < 3; ++j)
#pragma unroll
            for (int s = 0; s < 4; ++s)
                E[j * 4 + s] = __expf(sTr[j * NT + s]);

        const float* myF = sF + tid * FSTR;
        const int*   myT = sTg + tid * 9;

        int prev;
        if (tid > 0)            prev = sTg[(tid - 1) * 9 + (CH - 1)];
        else if (blockIdx.x)    prev = tags[start - 1];
        else                    prev = START_TAG;

        // step 0: A = diag(e) * E   (A_prev = I on live rows/cols)
        {
            const float f0 = myF[0], f1 = myF[1], f2 = myF[2];
            const float e0 = __expf(f0), e1 = __expf(f1), e2 = __expf(f2);
#pragma unroll
            for (int s = 0; s < 4; ++s) {
                A[0 * 4 + s] = e0 * E[0 * 4 + s];
                A[1 * 4 + s] = e1 * E[1 * 4 + s];
                A[2 * 4 + s] = e2 * E[2 * 4 + s];
            }
            const int tg = myT[0];
            gold = sTr[tg * NT + prev] + (tg == 0 ? f0 : (tg == 1 ? f1 : f2));
            prev = tg;
        }
        // steps 1..7
#pragma unroll
        for (int t = 1; t < CH; ++t) {
            const float f0 = myF[t * 3 + 0], f1 = myF[t * 3 + 1], f2 = myF[t * 3 + 2];
            const float e0 = __expf(f0), e1 = __expf(f1), e2 = __expf(f2);
            float N[12];
#pragma unroll
            for (int s = 0; s < 4; ++s) {
                const float a0 = A[0 * 4 + s], a1 = A[1 * 4 + s], a2 = A[2 * 4 + s];
                N[0 * 4 + s] = e0 * fmaf(E[0], a0, fmaf(E[1], a1, E[2] * a2));
                N[1 * 4 + s] = e1 * fmaf(E[4], a0, fmaf(E[5], a1, E[6] * a2));
                N[2 * 4 + s] = e2 * fmaf(E[8], a0, fmaf(E[9], a1, E[10] * a2));
            }
#pragma unroll
            for (int k = 0; k < 12; ++k) A[k] = N[k];

            const int tg = myT[t];
            gold += sTr[tg * NT + prev] + (tg == 0 ? f0 : (tg == 1 ? f1 : f2));
            prev = tg;
        }
        // normalize once per chunk (max growth ~e^75 from 1.0 — safe in fp32)
        float m = A[0];
#pragma unroll
        for (int k = 1; k < 12; ++k) m = fmaxf(m, A[k]);
        const float r = 1.0f / m;
#pragma unroll
        for (int k = 0; k < 12; ++k) A[k] *= r;
        off = __logf(m);

        if (start + CH == T_LEN) gold += sTr[STOP_TAG * NT + prev];
    } else {
#pragma unroll
        for (int k = 0; k < 12; ++k) A[k] = 0.0f;
    }

    // ---- block tree reduce (in time order), aliasing the stage buffers ----
    __syncthreads();                                 // done with sF/sTg
    float* sM = (float*)smem;                        // [256][13]
    float* sG = (float*)(smem + BTHR * 13 * 4);      // [256]

#pragma unroll
    for (int k = 0; k < 12; ++k) sM[tid * 13 + k] = A[k];
    sM[tid * 13 + 12] = off;
    sG[tid]           = gold;
    __syncthreads();

    for (int h = BTHR / 2; h >= 1; h >>= 1) {
        float C[13];
        float gg = 0.0f;
        const bool act = (tid < h);
        if (act) {
            float L[13], R[13];
#pragma unroll
            for (int k = 0; k < 13; ++k) {
                L[k] = sM[(2 * tid + 1) * 13 + k];
                R[k] = sM[(2 * tid) * 13 + k];
            }
            compose13(L, R, C);
            gg = sG[2 * tid] + sG[2 * tid + 1];
        }
        __syncthreads();
        if (act) {
#pragma unroll
            for (int k = 0; k < 13; ++k) sM[tid * 13 + k] = C[k];
            sG[tid] = gg;
        }
        __syncthreads();
    }

    if (tid < 13) ws[blockIdx.x * 13 + tid] = sM[tid];
    if (tid == 0) ws[GOFF + blockIdx.x] = sG[0];
}

__global__ __launch_bounds__(256) void crf_phase2(
    const float* __restrict__ trans, const float* __restrict__ ws,
    float* __restrict__ out)
{
    __shared__ float sM[256 * 13];
    __shared__ float sG[256];

    const int tid = threadIdx.x;

    // each thread composes 4 consecutive block matrices in time order
    {
        float acc[13], nxt[13], C[13];
#pragma unroll
        for (int k = 0; k < 13; ++k) acc[k] = ws[(4 * tid) * 13 + k];
        float gg = ws[GOFF + 4 * tid];
#pragma unroll
        for (int g = 1; g < 4; ++g) {
#pragma unroll
            for (int k = 0; k < 13; ++k) nxt[k] = ws[(4 * tid + g) * 13 + k];
            compose13(nxt, acc, C);
#pragma unroll
            for (int k = 0; k < 13; ++k) acc[k] = C[k];
            gg += ws[GOFF + 4 * tid + g];
        }
#pragma unroll
        for (int k = 0; k < 13; ++k) sM[tid * 13 + k] = acc[k];
        sG[tid] = gg;
    }
    __syncthreads();

    for (int h = 128; h >= 1; h >>= 1) {
        float C[13];
        float gg = 0.0f;
        const bool act = (tid < h);
        if (act) {
            float L[13], R[13];
#pragma unroll
            for (int k = 0; k < 13; ++k) {
                L[k] = sM[(2 * tid + 1) * 13 + k];
                R[k] = sM[(2 * tid) * 13 + k];
            }
            compose13(L, R, C);
            gg = sG[2 * tid] + sG[2 * tid + 1];
        }
        __syncthreads();
        if (act) {
#pragma unroll
            for (int k = 0; k < 13; ++k) sM[tid * 13 + k] = C[k];
            sG[tid] = gg;
        }
        __syncthreads();
    }

    if (tid == 0) {
        // alpha = off + log( sum_{j<3} M[j][START] * exp(trans[STOP][j]) )
        float s = 0.0f;
#pragma unroll
        for (int j = 0; j < 3; ++j)
            s += sM[j * 4 + 3] * __expf(trans[STOP_TAG * NT + j]);
        const float alpha = sM[12] + __logf(s);
        out[0] = alpha - sG[0];
    }
}

extern "C" void kernel_launch(void* const* d_in, const int* in_sizes, int n_in,
                              void* d_out, int out_size, void* d_ws, size_t ws_size,
                              hipStream_t stream) {
    const float* feats = (const float*)d_in[0];
    const int*   tags  = (const int*)d_in[1];
    const float* trans = (const float*)d_in[2];
    float*       out   = (float*)d_out;
    float*       ws    = (float*)d_ws;

    crf_phase1<<<NBLK, BTHR, 0, stream>>>(feats, tags, trans, ws);
    crf_phase2<<<1, 256, 0, stream>>>(trans, ws, out);
}